// Round 2
// baseline (174.762 us; speedup 1.0000x reference)
//
#include <hip/hip_runtime.h>

typedef unsigned short u16;
typedef unsigned int u32;
typedef short bf16x8 __attribute__((ext_vector_type(8)));
typedef float f32x4 __attribute__((ext_vector_type(4)));

#define HH 128

__device__ __forceinline__ u16 f2bf(float f) {
  u32 u = __float_as_uint(f);
  u += 0x7fffu + ((u >> 16) & 1u);  // round-to-nearest-even
  return (u16)(u >> 16);
}
__device__ __forceinline__ u32 pack2(float a, float b) {
  return (u32)f2bf(a) | ((u32)f2bf(b) << 16);
}

__device__ __forceinline__ void lds_dma16(const void* g, void* l) {
  __builtin_amdgcn_global_load_lds(
      (const __attribute__((address_space(1))) u32*)g,
      (__attribute__((address_space(3))) u32*)l, 16, 0, 0);
}

// ---------------------------------------------------------------------------
// Pre-pass: fused W_comb (bf16), chunk-transposed + bank-swizzled, into d_ws.
// Chunk index (((q*16+kc)*512+n)*4+p) holds W[k = kc*32 + lq*8 + j][col n],
// lq = p ^ (n&3) ^ ((n>>2)&3).
// Fused: k<384 -> W_cat[k][q*512+n]; k>=384 -> (n<128 ? 0 : W_exp[k-384][q*384+n-128])
// Coalesced via a 32x64 LDS tile transpose: contiguous float4 reads,
// contiguous uint4 writes.
// ---------------------------------------------------------------------------
__global__ __launch_bounds__(256) void prep_w(const float* __restrict__ Wcat,
                                              const float* __restrict__ Wexp,
                                              u16* __restrict__ Wc) {
  const int bx = blockIdx.x;      // 512 blocks: ((q*16+kc)*8 + nt)
  const int nt = bx & 7;
  const int kc = (bx >> 3) & 15;
  const int q = bx >> 7;
  __shared__ u16 T[32 * 72];      // [k-in-chunk][64 cols], stride 72 (pad)

  const int tid = threadIdx.x;
  // ---- load phase: row r (0..31), 8 consecutive cols ----
  const int r = tid >> 3;
  const int c8 = (tid & 7) * 8;
  float v[8];
  if (kc < 12) {
    const float* src =
        Wcat + (size_t)(kc * 32 + r) * 2048 + q * 512 + nt * 64 + c8;
    float4 a = *(const float4*)src;
    float4 b = *(const float4*)(src + 4);
    v[0] = a.x; v[1] = a.y; v[2] = a.z; v[3] = a.w;
    v[4] = b.x; v[5] = b.y; v[6] = b.z; v[7] = b.w;
  } else if (nt >= 2) {
    const float* src = Wexp + (size_t)((kc - 12) * 32 + r) * 1536 + q * 384 +
                       nt * 64 + c8 - 128;
    float4 a = *(const float4*)src;
    float4 b = *(const float4*)(src + 4);
    v[0] = a.x; v[1] = a.y; v[2] = a.z; v[3] = a.w;
    v[4] = b.x; v[5] = b.y; v[6] = b.z; v[7] = b.w;
  } else {
#pragma unroll
    for (int j = 0; j < 8; ++j) v[j] = 0.f;
  }
  uint4 pk;
  pk.x = pack2(v[0], v[1]);
  pk.y = pack2(v[2], v[3]);
  pk.z = pack2(v[4], v[5]);
  pk.w = pack2(v[6], v[7]);
  *(uint4*)&T[r * 72 + c8] = pk;
  __syncthreads();

  // ---- write phase: (nl, p) -> 16B chunk, fully coalesced store ----
  const int p = tid & 3;
  const int nl = tid >> 2;  // 0..63 local col
  const int lq = p ^ (nl & 3) ^ ((nl >> 2) & 3);
  u16 w[8];
#pragma unroll
  for (int j = 0; j < 8; ++j) w[j] = T[(lq * 8 + j) * 72 + nl];
  uint4 o;
  o.x = (u32)w[0] | ((u32)w[1] << 16);
  o.y = (u32)w[2] | ((u32)w[3] << 16);
  o.z = (u32)w[4] | ((u32)w[5] << 16);
  o.w = (u32)w[6] | ((u32)w[7] << 16);
  const size_t idx = ((size_t)((q * 16 + kc) * 512) + nt * 64 + nl) * 4 + p;
  ((uint4*)Wc)[idx] = o;
}

// ---------------------------------------------------------------------------
// Fused GEMM + gate epilogue.
// Block: one (b,q) group x 64-row tile x 64-wide h-slab (x all 4 gate groups
// so the softmax coupling stays register-local). 4 waves; wave w owns all 64
// rows and columns {gg*128 + h0 + w*16 + c}, gg 0..3.
// acc = 16 f32x4/wave (64 regs) -> launch_bounds(256,3) for 3 blocks/CU.
// ---------------------------------------------------------------------------
__global__ __launch_bounds__(256, 3) void fused_gate(
    const float* __restrict__ CNN, const float* __restrict__ gaz,
    const float* __restrict__ gazb, const float* __restrict__ gm,
    const float* __restrict__ exper, const u16* __restrict__ Wc,
    const float* __restrict__ bcat, const float* __restrict__ bexp,
    float* __restrict__ out) {
  __shared__ u16 Abuf[64 * 32];   // 4 KB
  __shared__ u16 Wbuf[256 * 32];  // 16 KB, [c = gg*64+hl][k-chunk] swizzled

  const int tid = threadIdx.x;
  const int bx = blockIdx.x;      // 2048: grp*16 + tile*2 + half
  const int half = bx & 1;
  const int tile = (bx >> 1) & 7;
  const int grp = bx >> 4;
  const int b = grp >> 2;
  const int q = grp & 3;
  const int s_base = tile * 64;
  const int h0 = half * 64;
  const int lane = tid & 63;
  const int wave = tid >> 6;
  const int l15 = lane & 15;
  const int quad = lane >> 4;
  const int physq = quad ^ (l15 & 3) ^ ((l15 >> 2) & 3);  // XOR bank swizzle

  // A-staging assignment: thread -> (row, phys 16B slot)
  const int arow = tid >> 2;  // 0..63
  const int ap = tid & 3;
  const int alq = ap ^ (arow & 3) ^ ((arow >> 2) & 3);
  const int srow = s_base + arow;
  const float* s0 = CNN + (size_t)(b * 2048 + q * 512 + srow) * HH;
  const float* s1 = ((q & 1) ? gazb : gaz) + (size_t)(b * 512 + srow) * HH;
  const float* s2 = gm + (size_t)(b * 512 + srow) * HH;
  const float* s3 = exper + (size_t)(b * 512 + srow) * HH;

  const u16* wsrc = Wc + (size_t)q * 16 * 512 * 32;

  f32x4 acc[4][4];  // [row-tile][gate-group]
#pragma unroll
  for (int rt = 0; rt < 4; ++rt)
#pragma unroll
    for (int gg = 0; gg < 4; ++gg) acc[rt][gg] = (f32x4)0.f;

  for (int kc = 0; kc < 16; ++kc) {
    // ---- stage A: gather 8 fp32 from the right source, convert to bf16 ----
    const int k0 = kc * 32 + alq * 8;
    const int sel = k0 >> 7;
    const float* sp = (sel == 0) ? s0 : (sel == 1) ? s1 : (sel == 2) ? s2 : s3;
    sp += (k0 & 127);
    float4 f0 = *(const float4*)sp;
    float4 f1 = *(const float4*)(sp + 4);
    uint4 pk;
    pk.x = pack2(f0.x, f0.y);
    pk.y = pack2(f0.z, f0.w);
    pk.z = pack2(f1.x, f1.y);
    pk.w = pack2(f1.z, f1.w);
    *(uint4*)&Abuf[arow * 32 + ap * 8] = pk;

    // ---- stage W: 4 x 1KB async DMA per wave (wave w loads gg = w) ----
    const u16* wchunk = wsrc + (size_t)kc * 512 * 32;
#pragma unroll
    for (int i = 0; i < 4; ++i) {
      const int n0 = wave * 128 + h0 + i * 16;
      lds_dma16(wchunk + (size_t)n0 * 32 + lane * 8,
                &Wbuf[(wave * 64 + i * 16) * 32]);
    }
    __syncthreads();

    // ---- fragments + MFMA ----
    bf16x8 af[4];
#pragma unroll
    for (int rt = 0; rt < 4; ++rt)
      af[rt] = *(const bf16x8*)&Abuf[(rt * 16 + l15) * 32 + physq * 8];
    bf16x8 bfr[4];
#pragma unroll
    for (int gg = 0; gg < 4; ++gg) {
      const int c = gg * 64 + wave * 16 + l15;
      bfr[gg] = *(const bf16x8*)&Wbuf[c * 32 + physq * 8];
    }
#pragma unroll
    for (int rt = 0; rt < 4; ++rt)
#pragma unroll
      for (int gg = 0; gg < 4; ++gg)
        acc[rt][gg] = __builtin_amdgcn_mfma_f32_16x16x32_bf16(
            af[rt], bfr[gg], acc[rt][gg], 0, 0, 0);
    __syncthreads();
  }

  // ---- epilogue: tanh / sigmoid / softmax-of-3 / weighted state sum ----
  const float* bcq = bcat + q * 512;
  const float* beq = bexp + q * 384;
  const size_t cnnbase = (size_t)(b * 2048 + q * 512 + s_base) * HH;
  const size_t expbase = (size_t)(b * 512 + s_base) * HH;
  const size_t outbase = (size_t)((q * 32 + b) * 512 + s_base) * HH;
  const int h = h0 + wave * 16 + l15;
  const float bc0 = bcq[h];
  const float bc1 = bcq[128 + h];
  const float bc2 = bcq[256 + h];
  const float bc3 = bcq[384 + h];
  const float be1 = beq[h];
  const float be2 = beq[128 + h];
  const float be3 = beq[256 + h];
#pragma unroll
  for (int rt = 0; rt < 4; ++rt) {
#pragma unroll
    for (int r = 0; r < 4; ++r) {
      const int row = rt * 16 + quad * 4 + r;
      const float c0 = acc[rt][0][r] + bc0;
      const float p1 = acc[rt][1][r] + bc1 + be1;
      const float p2 = acc[rt][2][r] + bc2 + be2;
      const float p3 = acc[rt][3][r] + bc3 + be3;
      const float e2c = __expf(2.f * c0);
      const float ns = 1.f - 2.f * __builtin_amdgcn_rcpf(e2c + 1.f);  // tanh
      const float g1 = __builtin_amdgcn_rcpf(1.f + __expf(-p1));
      const float g2 = __builtin_amdgcn_rcpf(1.f + __expf(-p2));
      const float g3 = __builtin_amdgcn_rcpf(1.f + __expf(-p3));
      const float e1 = __expf(g1);
      const float e2 = __expf(g2);
      const float e3 = __expf(g3);
      const float inv = __builtin_amdgcn_rcpf(e1 + e2 + e3);
      const float cnn = CNN[cnnbase + (size_t)row * HH + h];
      const float ex = exper[expbase + (size_t)row * HH + h];
      out[outbase + (size_t)row * HH + h] = (e1 * ns + e2 * cnn + e3 * ex) * inv;
    }
  }
}

extern "C" void kernel_launch(void* const* d_in, const int* in_sizes, int n_in,
                              void* d_out, int out_size, void* d_ws, size_t ws_size,
                              hipStream_t stream) {
  const float* CNN = (const float*)d_in[0];
  const float* gaz = (const float*)d_in[1];
  const float* gazb = (const float*)d_in[2];
  const float* gm = (const float*)d_in[3];
  const float* exper = (const float*)d_in[4];
  const float* Wcat = (const float*)d_in[5];
  const float* bcat = (const float*)d_in[6];
  const float* Wexp = (const float*)d_in[7];
  const float* bexp = (const float*)d_in[8];
  u16* Wc = (u16*)d_ws;  // 2 MB fused bf16 weights

  prep_w<<<512, 256, 0, stream>>>(Wcat, Wexp, Wc);
  fused_gate<<<2048, 256, 0, stream>>>(CNN, gaz, gazb, gm, exper, Wc, bcat,
                                       bexp, (float*)d_out);
}

// Round 3
// 169.874 us; speedup vs baseline: 1.0288x; 1.0288x over previous
//
#include <hip/hip_runtime.h>

typedef unsigned short u16;
typedef unsigned int u32;
typedef short bf16x8 __attribute__((ext_vector_type(8)));
typedef float f32x4 __attribute__((ext_vector_type(4)));

#define HH 128

__device__ __forceinline__ u16 f2bf(float f) {
  u32 u = __float_as_uint(f);
  u += 0x7fffu + ((u >> 16) & 1u);  // round-to-nearest-even
  return (u16)(u >> 16);
}
__device__ __forceinline__ u32 pack2(float a, float b) {
  return (u32)f2bf(a) | ((u32)f2bf(b) << 16);
}
__device__ __forceinline__ float bf2f(u16 h) {
  return __uint_as_float(((u32)h) << 16);
}

// ---------------------------------------------------------------------------
// Pre-pass: fused W_comb (bf16), chunk-transposed + bank-swizzled, into d_ws.
// Chunk index (((q*16+kc)*512+n)*4+p) holds W[k = kc*32 + lq*8 + j][col n],
// lq = p ^ (n&3) ^ ((n>>2)&3).
// Fused: k<384 -> W_cat[k][q*512+n]; k>=384 -> (n<128 ? 0 : W_exp[k-384][q*384+n-128])
// ---------------------------------------------------------------------------
__global__ __launch_bounds__(256) void prep_w(const float* __restrict__ Wcat,
                                              const float* __restrict__ Wexp,
                                              u16* __restrict__ Wc) {
  const int bx = blockIdx.x;      // 512 blocks: ((q*16+kc)*8 + nt)
  const int nt = bx & 7;
  const int kc = (bx >> 3) & 15;
  const int q = bx >> 7;
  __shared__ u16 T[32 * 72];      // [k-in-chunk][64 cols], stride 72 (pad)

  const int tid = threadIdx.x;
  const int r = tid >> 3;
  const int c8 = (tid & 7) * 8;
  float v[8];
  if (kc < 12) {
    const float* src =
        Wcat + (size_t)(kc * 32 + r) * 2048 + q * 512 + nt * 64 + c8;
    float4 a = *(const float4*)src;
    float4 b = *(const float4*)(src + 4);
    v[0] = a.x; v[1] = a.y; v[2] = a.z; v[3] = a.w;
    v[4] = b.x; v[5] = b.y; v[6] = b.z; v[7] = b.w;
  } else if (nt >= 2) {
    const float* src = Wexp + (size_t)((kc - 12) * 32 + r) * 1536 + q * 384 +
                       nt * 64 + c8 - 128;
    float4 a = *(const float4*)src;
    float4 b = *(const float4*)(src + 4);
    v[0] = a.x; v[1] = a.y; v[2] = a.z; v[3] = a.w;
    v[4] = b.x; v[5] = b.y; v[6] = b.z; v[7] = b.w;
  } else {
#pragma unroll
    for (int j = 0; j < 8; ++j) v[j] = 0.f;
  }
  uint4 pk;
  pk.x = pack2(v[0], v[1]);
  pk.y = pack2(v[2], v[3]);
  pk.z = pack2(v[4], v[5]);
  pk.w = pack2(v[6], v[7]);
  *(uint4*)&T[r * 72 + c8] = pk;
  __syncthreads();

  const int p = tid & 3;
  const int nl = tid >> 2;  // 0..63 local col
  const int lq = p ^ (nl & 3) ^ ((nl >> 2) & 3);
  u16 w[8];
#pragma unroll
  for (int j = 0; j < 8; ++j) w[j] = T[(lq * 8 + j) * 72 + nl];
  uint4 o;
  o.x = (u32)w[0] | ((u32)w[1] << 16);
  o.y = (u32)w[2] | ((u32)w[3] << 16);
  o.z = (u32)w[4] | ((u32)w[5] << 16);
  o.w = (u32)w[6] | ((u32)w[7] << 16);
  const size_t idx = ((size_t)((q * 16 + kc) * 512) + nt * 64 + nl) * 4 + p;
  ((uint4*)Wc)[idx] = o;
}

// ---------------------------------------------------------------------------
// Fused GEMM + gate epilogue — barrier-free K-loop.
// Block: (b,q) x 64-row tile x 64-wide h-slab. A (64x512, bf16) staged fully
// in LDS with ONE barrier; B streamed global->VGPR (W_comb is L2-resident),
// double-buffered. Epilogue reads CNN/exper back out of the A LDS buffer.
// A LDS layout: [kc][row][32k] with physical octet p = o ^ s(row) ^ (kc>>2),
// s(row) = (row&3)^((row>>2)&3)  -> uniform 8-way b128 access (the minimum).
// ---------------------------------------------------------------------------
__global__ __launch_bounds__(256, 2) void fused_gate(
    const float* __restrict__ CNN, const float* __restrict__ gaz,
    const float* __restrict__ gazb, const float* __restrict__ gm,
    const float* __restrict__ exper, const u16* __restrict__ Wc,
    const float* __restrict__ bcat, const float* __restrict__ bexp,
    float* __restrict__ out) {
  __shared__ u16 Abuf[16 * 64 * 32];  // 64 KB

  const int tid = threadIdx.x;
  const int lane = tid & 63;
  const int wave = tid >> 6;
  const int bx = blockIdx.x;  // 2048: grp*16 + tile*2 + half
  const int half = bx & 1;
  const int tile = (bx >> 1) & 7;
  const int grp = bx >> 4;
  const int b = grp >> 2;
  const int q = grp & 3;
  const int s_base = tile * 64;
  const int h0 = half * 64;

  // ---- stage A: wave w loads source w (k-range [w*128,(w+1)*128)) ----
  const float* src_w =
      (wave == 0) ? CNN + (size_t)(b * 2048 + q * 512 + s_base) * HH
      : (wave == 1) ? (((q & 1) ? gazb : gaz) + (size_t)(b * 512 + s_base) * HH)
      : (wave == 2) ? gm + (size_t)(b * 512 + s_base) * HH
                    : exper + (size_t)(b * 512 + s_base) * HH;
#pragma unroll
  for (int t = 0; t < 16; ++t) {
    const int s = t * 64 + lane;
    const int row = s >> 4;       // 0..63
    const int oct = s & 15;       // 16B-octet within the 128-feature row
    const float* sp = src_w + (size_t)row * HH + oct * 8;
    float4 f0 = *(const float4*)sp;
    float4 f1 = *(const float4*)(sp + 4);
    uint4 pk;
    pk.x = pack2(f0.x, f0.y);
    pk.y = pack2(f0.z, f0.w);
    pk.z = pack2(f1.x, f1.y);
    pk.w = pack2(f1.z, f1.w);
    const int kc = wave * 4 + (oct >> 2);
    const int o = oct & 3;
    const int ph = o ^ ((row & 3) ^ ((row >> 2) & 3)) ^ wave;  // kc>>2 == wave
    *(uint4*)&Abuf[(kc * 64 + row) * 32 + ph * 8] = pk;
  }
  __syncthreads();

  // ---- K-loop: barrier-free, B double-buffered from global ----
  const int l15 = lane & 15;
  const int quad = lane >> 4;
  const int sl = (l15 & 3) ^ ((l15 >> 2) & 3);
  const int physB = quad ^ sl;

  const u16* wp[4];
#pragma unroll
  for (int gg = 0; gg < 4; ++gg) {
    const int n = gg * 128 + h0 + wave * 16 + l15;
    wp[gg] = Wc + (((size_t)(q * 16) * 512 + n) * 4 + physB) * 8;
  }

  f32x4 acc[4][4];
#pragma unroll
  for (int rt = 0; rt < 4; ++rt)
#pragma unroll
    for (int gg = 0; gg < 4; ++gg) acc[rt][gg] = (f32x4)0.f;

  bf16x8 bcur[4], bnxt[4];
#pragma unroll
  for (int gg = 0; gg < 4; ++gg) bcur[gg] = *(const bf16x8*)wp[gg];

#pragma unroll
  for (int kc = 0; kc < 16; ++kc) {
    if (kc < 15) {
#pragma unroll
      for (int gg = 0; gg < 4; ++gg)
        bnxt[gg] = *(const bf16x8*)(wp[gg] + (size_t)(kc + 1) * 16384);
    }
    const int pa = (quad ^ sl ^ (kc >> 2)) * 8;
    bf16x8 af[4];
#pragma unroll
    for (int rt = 0; rt < 4; ++rt)
      af[rt] = *(const bf16x8*)&Abuf[(kc * 64 + rt * 16 + l15) * 32 + pa];
#pragma unroll
    for (int rt = 0; rt < 4; ++rt)
#pragma unroll
      for (int gg = 0; gg < 4; ++gg)
        acc[rt][gg] = __builtin_amdgcn_mfma_f32_16x16x32_bf16(
            af[rt], bcur[gg], acc[rt][gg], 0, 0, 0);
#pragma unroll
    for (int gg = 0; gg < 4; ++gg) bcur[gg] = bnxt[gg];
  }

  // ---- epilogue: tanh / sigmoid / softmax-of-3 / weighted state sum ----
  const float* bcq = bcat + q * 512;
  const float* beq = bexp + q * 384;
  const size_t outbase = (size_t)((q * 32 + b) * 512 + s_base) * HH;
  const int h = h0 + wave * 16 + l15;
  const float bc0 = bcq[h];
  const float bc1 = bcq[128 + h];
  const float bc2 = bcq[256 + h];
  const float bc3 = bcq[384 + h];
  const float be1 = beq[h];
  const float be2 = beq[128 + h];
  const float be3 = beq[256 + h];
  const int kcc = h >> 5;        // CNN chunk (0..3)
  const int kce = 12 + (h >> 5); // exper chunk (12..15)
  const int oh = (h >> 3) & 3;
  const int he = h & 7;
#pragma unroll
  for (int rt = 0; rt < 4; ++rt) {
#pragma unroll
    for (int r = 0; r < 4; ++r) {
      const int row = rt * 16 + quad * 4 + r;
      const int srw = (row & 3) ^ ((row >> 2) & 3);
      const float cnn = bf2f(Abuf[(kcc * 64 + row) * 32 + (oh ^ srw) * 8 + he]);
      const float ex =
          bf2f(Abuf[(kce * 64 + row) * 32 + (oh ^ srw ^ 3) * 8 + he]);
      const float c0 = acc[rt][0][r] + bc0;
      const float p1 = acc[rt][1][r] + bc1 + be1;
      const float p2 = acc[rt][2][r] + bc2 + be2;
      const float p3 = acc[rt][3][r] + bc3 + be3;
      const float e2c = __expf(2.f * c0);
      const float ns = 1.f - 2.f * __builtin_amdgcn_rcpf(e2c + 1.f);  // tanh
      const float g1 = __builtin_amdgcn_rcpf(1.f + __expf(-p1));
      const float g2 = __builtin_amdgcn_rcpf(1.f + __expf(-p2));
      const float g3 = __builtin_amdgcn_rcpf(1.f + __expf(-p3));
      const float e1 = __expf(g1);
      const float e2 = __expf(g2);
      const float e3 = __expf(g3);
      const float inv = __builtin_amdgcn_rcpf(e1 + e2 + e3);
      out[outbase + (size_t)row * HH + h] = (e1 * ns + e2 * cnn + e3 * ex) * inv;
    }
  }
}

extern "C" void kernel_launch(void* const* d_in, const int* in_sizes, int n_in,
                              void* d_out, int out_size, void* d_ws, size_t ws_size,
                              hipStream_t stream) {
  const float* CNN = (const float*)d_in[0];
  const float* gaz = (const float*)d_in[1];
  const float* gazb = (const float*)d_in[2];
  const float* gm = (const float*)d_in[3];
  const float* exper = (const float*)d_in[4];
  const float* Wcat = (const float*)d_in[5];
  const float* bcat = (const float*)d_in[6];
  const float* Wexp = (const float*)d_in[7];
  const float* bexp = (const float*)d_in[8];
  u16* Wc = (u16*)d_ws;  // 2 MB fused bf16 weights

  prep_w<<<512, 256, 0, stream>>>(Wcat, Wexp, Wc);
  fused_gate<<<2048, 256, 0, stream>>>(CNN, gaz, gazb, gm, exper, Wc, bcat,
                                       bexp, (float*)d_out);
}

// Round 4
// 155.882 us; speedup vs baseline: 1.1211x; 1.0898x over previous
//
#include <hip/hip_runtime.h>

typedef unsigned short u16;
typedef unsigned int u32;
typedef short bf16x8 __attribute__((ext_vector_type(8)));
typedef float f32x4 __attribute__((ext_vector_type(4)));

#define HH 128

__device__ __forceinline__ u16 f2bf(float f) {
  u32 u = __float_as_uint(f);
  u += 0x7fffu + ((u >> 16) & 1u);  // round-to-nearest-even
  return (u16)(u >> 16);
}
__device__ __forceinline__ u32 pack2(float a, float b) {
  return (u32)f2bf(a) | ((u32)f2bf(b) << 16);
}
__device__ __forceinline__ float bf2f(u16 h) {
  return __uint_as_float(((u32)h) << 16);
}

// ---------------------------------------------------------------------------
// Pre-pass: fused W_comb (bf16), chunk-transposed + bank-swizzled, into d_ws.
// Chunk index (((q*16+kc)*512+n)*4+p) holds W[k = kc*32 + lq*8 + j][col n],
// lq = p ^ (n&3) ^ ((n>>2)&3).
// Fused: k<384 -> W_cat[k][q*512+n]; k>=384 -> (n<128 ? 0 : W_exp[k-384][q*384+n-128])
// ---------------------------------------------------------------------------
__global__ __launch_bounds__(256) void prep_w(const float* __restrict__ Wcat,
                                              const float* __restrict__ Wexp,
                                              u16* __restrict__ Wc) {
  const int bx = blockIdx.x;      // 512 blocks: ((q*16+kc)*8 + nt)
  const int nt = bx & 7;
  const int kc = (bx >> 3) & 15;
  const int q = bx >> 7;
  __shared__ u16 T[32 * 72];      // [k-in-chunk][64 cols], stride 72 (pad)

  const int tid = threadIdx.x;
  const int r = tid >> 3;
  const int c8 = (tid & 7) * 8;
  float v[8];
  if (kc < 12) {
    const float* src =
        Wcat + (size_t)(kc * 32 + r) * 2048 + q * 512 + nt * 64 + c8;
    float4 a = *(const float4*)src;
    float4 b = *(const float4*)(src + 4);
    v[0] = a.x; v[1] = a.y; v[2] = a.z; v[3] = a.w;
    v[4] = b.x; v[5] = b.y; v[6] = b.z; v[7] = b.w;
  } else if (nt >= 2) {
    const float* src = Wexp + (size_t)((kc - 12) * 32 + r) * 1536 + q * 384 +
                       nt * 64 + c8 - 128;
    float4 a = *(const float4*)src;
    float4 b = *(const float4*)(src + 4);
    v[0] = a.x; v[1] = a.y; v[2] = a.z; v[3] = a.w;
    v[4] = b.x; v[5] = b.y; v[6] = b.z; v[7] = b.w;
  } else {
#pragma unroll
    for (int j = 0; j < 8; ++j) v[j] = 0.f;
  }
  uint4 pk;
  pk.x = pack2(v[0], v[1]);
  pk.y = pack2(v[2], v[3]);
  pk.z = pack2(v[4], v[5]);
  pk.w = pack2(v[6], v[7]);
  *(uint4*)&T[r * 72 + c8] = pk;
  __syncthreads();

  const int p = tid & 3;
  const int nl = tid >> 2;  // 0..63 local col
  const int lq = p ^ (nl & 3) ^ ((nl >> 2) & 3);
  u16 w[8];
#pragma unroll
  for (int j = 0; j < 8; ++j) w[j] = T[(lq * 8 + j) * 72 + nl];
  uint4 o;
  o.x = (u32)w[0] | ((u32)w[1] << 16);
  o.y = (u32)w[2] | ((u32)w[3] << 16);
  o.z = (u32)w[4] | ((u32)w[5] << 16);
  o.w = (u32)w[6] | ((u32)w[7] << 16);
  const size_t idx = ((size_t)((q * 16 + kc) * 512) + nt * 64 + nl) * 4 + p;
  ((uint4*)Wc)[idx] = o;
}

// ---------------------------------------------------------------------------
// Fused GEMM + gate epilogue — barrier-free K-loop, 8-wave blocks.
// Block: (b,q) x 64-row tile x FULL 128-h slab. 8 waves; wave w owns columns
// {gg*128 + w*16 + c}, gg 0..3 (softmax-coupled, register-local).
// A (64x512 bf16, 64 KB) staged once with ONE barrier, shared by all 8 waves;
// B streamed global->VGPR (W_comb L2-resident), 1-deep prefetch.
// 2 blocks/CU (128 KB LDS) = 16 waves/CU = 4 waves/SIMD.
// A LDS layout: [kc][row][32k], physical octet p = o ^ s(row) ^ (kc>>2),
// s(row) = (row&3)^((row>>2)&3).
// ---------------------------------------------------------------------------
__global__ __launch_bounds__(512, 4) void fused_gate(
    const float* __restrict__ CNN, const float* __restrict__ gaz,
    const float* __restrict__ gazb, const float* __restrict__ gm,
    const float* __restrict__ exper, const u16* __restrict__ Wc,
    const float* __restrict__ bcat, const float* __restrict__ bexp,
    float* __restrict__ out) {
  __shared__ u16 Abuf[16 * 64 * 32];  // 64 KB

  const int tid = threadIdx.x;
  const int lane = tid & 63;
  const int wave = tid >> 6;  // 0..7
  const int bx = blockIdx.x;  // 1024: grp*8 + tile
  const int tile = bx & 7;
  const int grp = bx >> 3;
  const int b = grp >> 2;
  const int q = grp & 3;
  const int s_base = tile * 64;

  // ---- stage A: wave pair (sel = wave>>1) loads source sel; wave&1 picks
  //      the 32-row half. Each wave: 32 rows x 128 feats (16 KB fp32).
  const int sel = wave >> 1;
  const float* src_w =
      (sel == 0) ? CNN + (size_t)(b * 2048 + q * 512 + s_base) * HH
      : (sel == 1) ? (((q & 1) ? gazb : gaz) + (size_t)(b * 512 + s_base) * HH)
      : (sel == 2) ? gm + (size_t)(b * 512 + s_base) * HH
                   : exper + (size_t)(b * 512 + s_base) * HH;
#pragma unroll
  for (int t = 0; t < 8; ++t) {
    const int s = t * 64 + lane;            // 0..511
    const int row = (wave & 1) * 32 + (s >> 4);
    const int oct = s & 15;                 // 16B-octet within 128-feat row
    const float* sp = src_w + (size_t)row * HH + oct * 8;
    float4 f0 = *(const float4*)sp;
    float4 f1 = *(const float4*)(sp + 4);
    uint4 pk;
    pk.x = pack2(f0.x, f0.y);
    pk.y = pack2(f0.z, f0.w);
    pk.z = pack2(f1.x, f1.y);
    pk.w = pack2(f1.z, f1.w);
    const int kc = sel * 4 + (oct >> 2);
    const int o = oct & 3;
    const int ph = o ^ ((row & 3) ^ ((row >> 2) & 3)) ^ sel;  // kc>>2 == sel
    *(uint4*)&Abuf[(kc * 64 + row) * 32 + ph * 8] = pk;
  }
  __syncthreads();

  // ---- K-loop: barrier-free, B 1-deep prefetch from global (L2) ----
  const int l15 = lane & 15;
  const int quad = lane >> 4;
  const int sl = (l15 & 3) ^ ((l15 >> 2) & 3);
  const int physB = quad ^ sl;

  const u16* wp[4];
#pragma unroll
  for (int gg = 0; gg < 4; ++gg) {
    const int n = gg * 128 + wave * 16 + l15;
    wp[gg] = Wc + (((size_t)(q * 16) * 512 + n) * 4 + physB) * 8;
  }

  f32x4 acc[4][4];
#pragma unroll
  for (int rt = 0; rt < 4; ++rt)
#pragma unroll
    for (int gg = 0; gg < 4; ++gg) acc[rt][gg] = (f32x4)0.f;

  bf16x8 bcur[4], bnxt[4];
#pragma unroll
  for (int gg = 0; gg < 4; ++gg) bcur[gg] = *(const bf16x8*)wp[gg];

#pragma unroll
  for (int kc = 0; kc < 16; ++kc) {
    if (kc < 15) {
#pragma unroll
      for (int gg = 0; gg < 4; ++gg)
        bnxt[gg] = *(const bf16x8*)(wp[gg] + (size_t)(kc + 1) * 16384);
    }
    const int pa = (quad ^ sl ^ (kc >> 2)) * 8;
    bf16x8 af[4];
#pragma unroll
    for (int rt = 0; rt < 4; ++rt)
      af[rt] = *(const bf16x8*)&Abuf[(kc * 64 + rt * 16 + l15) * 32 + pa];
#pragma unroll
    for (int rt = 0; rt < 4; ++rt)
#pragma unroll
      for (int gg = 0; gg < 4; ++gg)
        acc[rt][gg] = __builtin_amdgcn_mfma_f32_16x16x32_bf16(
            af[rt], bcur[gg], acc[rt][gg], 0, 0, 0);
#pragma unroll
    for (int gg = 0; gg < 4; ++gg) bcur[gg] = bnxt[gg];
  }

  // ---- epilogue: tanh / sigmoid / softmax-of-3 / weighted state sum ----
  const float* bcq = bcat + q * 512;
  const float* beq = bexp + q * 384;
  const size_t outbase = (size_t)((q * 32 + b) * 512 + s_base) * HH;
  const int h = wave * 16 + l15;  // 0..127
  const float bc0 = bcq[h];
  const float bc1 = bcq[128 + h];
  const float bc2 = bcq[256 + h];
  const float bc3 = bcq[384 + h];
  const float be1 = beq[h];
  const float be2 = beq[128 + h];
  const float be3 = beq[256 + h];
  const int kcc = h >> 5;         // CNN chunk (0..3)
  const int kce = 12 + (h >> 5);  // exper chunk (12..15)
  const int oh = (h >> 3) & 3;
  const int he = h & 7;
#pragma unroll
  for (int rt = 0; rt < 4; ++rt) {
#pragma unroll
    for (int r = 0; r < 4; ++r) {
      const int row = rt * 16 + quad * 4 + r;
      const int srw = (row & 3) ^ ((row >> 2) & 3);
      const float cnn = bf2f(Abuf[(kcc * 64 + row) * 32 + (oh ^ srw) * 8 + he]);
      const float ex =
          bf2f(Abuf[(kce * 64 + row) * 32 + (oh ^ srw ^ 3) * 8 + he]);
      const float c0 = acc[rt][0][r] + bc0;
      const float p1 = acc[rt][1][r] + bc1 + be1;
      const float p2 = acc[rt][2][r] + bc2 + be2;
      const float p3 = acc[rt][3][r] + bc3 + be3;
      const float e2c = __expf(2.f * c0);
      const float ns = 1.f - 2.f * __builtin_amdgcn_rcpf(e2c + 1.f);  // tanh
      const float g1 = __builtin_amdgcn_rcpf(1.f + __expf(-p1));
      const float g2 = __builtin_amdgcn_rcpf(1.f + __expf(-p2));
      const float g3 = __builtin_amdgcn_rcpf(1.f + __expf(-p3));
      const float e1 = __expf(g1);
      const float e2 = __expf(g2);
      const float e3 = __expf(g3);
      const float inv = __builtin_amdgcn_rcpf(e1 + e2 + e3);
      out[outbase + (size_t)row * HH + h] = (e1 * ns + e2 * cnn + e3 * ex) * inv;
    }
  }
}

extern "C" void kernel_launch(void* const* d_in, const int* in_sizes, int n_in,
                              void* d_out, int out_size, void* d_ws, size_t ws_size,
                              hipStream_t stream) {
  const float* CNN = (const float*)d_in[0];
  const float* gaz = (const float*)d_in[1];
  const float* gazb = (const float*)d_in[2];
  const float* gm = (const float*)d_in[3];
  const float* exper = (const float*)d_in[4];
  const float* Wcat = (const float*)d_in[5];
  const float* bcat = (const float*)d_in[6];
  const float* Wexp = (const float*)d_in[7];
  const float* bexp = (const float*)d_in[8];
  u16* Wc = (u16*)d_ws;  // 2 MB fused bf16 weights

  prep_w<<<512, 256, 0, stream>>>(Wcat, Wexp, Wc);
  fused_gate<<<1024, 512, 0, stream>>>(CNN, gaz, gazb, gm, exper, Wc, bcat,
                                       bexp, (float*)d_out);
}